// Round 4
// baseline (780.017 us; speedup 1.0000x reference)
//
#include <hip/hip_runtime.h>
#include <math.h>

#define N_NODES 50000
#define N_EDGES 800000
#define SCAN_B 512
#define SCAN_NBLK ((N_NODES + SCAN_B - 1) / SCAN_B)   // 98

typedef unsigned short u16;
typedef unsigned int u32;
typedef _Float16 f16;
typedef __fp16 h2 __attribute__((ext_vector_type(2)));   // matches cvt_pkrtz / fdot2

union U32H2 { u32 u; h2 h; };
__device__ __forceinline__ h2 u2h(u32 x) { U32H2 t; t.u = x; return t.h; }
__device__ __forceinline__ u32 h2u(h2 x) { U32H2 t; t.h = x; return t.u; }

// DPP cross-lane move (VALU pipe). CTRL: 0xB1=xor1(quad), 0x4E=xor2(quad),
// 0x124=row_ror:4, 0x128=row_ror:8. Rotation-reduce: every lane of a 16-row
// ends with the row sum after steps 1,2,ror4,ror8.
template<int CTRL>
__device__ __forceinline__ h2 dppmov(h2 x) {
    return u2h((u32)__builtin_amdgcn_update_dpp(0, (int)h2u(x), CTRL, 0xF, 0xF, true));
}
__device__ __forceinline__ h2 swz16(h2 x) {   // lane ^= 16 within each 32-group
    return u2h((u32)__builtin_amdgcn_ds_swizzle((int)h2u(x), 0x401F));
}

// ---------------- K0: edge MLP (f16 out) + fused degree count ----------------
__global__ void k_edge_mlp(const float* __restrict__ edge_attr,
                           const float* __restrict__ Wm1, const float* __restrict__ bm1,
                           const float* __restrict__ Wm2, const float* __restrict__ bm2,
                           const int* __restrict__ dst, int* __restrict__ deg,
                           f16* __restrict__ e16) {
    int e = blockIdx.x * blockDim.x + threadIdx.x;
    if (e >= N_EDGES) return;
    atomicAdd(&deg[dst[e]], 1);
    const float4* ap = (const float4*)(edge_attr + (size_t)e * 16);
    float a[16];
    #pragma unroll
    for (int i = 0; i < 4; i++) {
        float4 r = ap[i];
        a[4*i] = r.x; a[4*i+1] = r.y; a[4*i+2] = r.z; a[4*i+3] = r.w;
    }
    float g1[16];
    #pragma unroll
    for (int j = 0; j < 16; j++) {
        float v = bm1[j];
        #pragma unroll
        for (int k = 0; k < 16; k++) v = fmaf(a[k], Wm1[k*16 + j], v);
        g1[j] = 0.5f * v * (1.0f + erff(v * 0.70710678118654752f));
    }
    float o[16];
    #pragma unroll
    for (int j = 0; j < 16; j++) {
        float v = bm2[j];
        #pragma unroll
        for (int k = 0; k < 16; k++) v = fmaf(g1[k], Wm2[k*16 + j], v);
        o[j] = v;
    }
    u32 w[8];
    #pragma unroll
    for (int k2 = 0; k2 < 8; k2++) w[k2] = h2u(__builtin_amdgcn_cvt_pkrtz(o[2*k2], o[2*k2+1]));
    uint4* op = (uint4*)(e16 + (size_t)e * 16);
    op[0] = make_uint4(w[0], w[1], w[2], w[3]);
    op[1] = make_uint4(w[4], w[5], w[6], w[7]);
}

// ---------------- K1: node features -> XLt/XRt [n][c][8 inst] f16 ------------
// 512 threads = 8 waves: wave w<4 -> XL side gate w; w>=4 -> XR side gate w-4.
template<int K>
__global__ void __launch_bounds__(512)
k_node_feats(const float* __restrict__ in,
             const float* __restrict__ Wl, const float* __restrict__ bl,
             const float* __restrict__ Wr, const float* __restrict__ br,
             f16* __restrict__ XLt, f16* __restrict__ XRt, int inst_base) {
    int w = threadIdx.x >> 6;
    int c = threadIdx.x & 63;
    int g = w & 3;
    bool isR = w >= 4;
    const float* W = isR ? Wr : Wl;
    const float* bias = isR ? br : bl;
    f16* out = isR ? XRt : XLt;
    int inst = inst_base + g;
    float wcol[K];
    #pragma unroll
    for (int k = 0; k < K; k++) wcol[k] = W[(g*K + k)*64 + c];
    float b = bias[g*64 + c];
    for (int n = blockIdx.x; n < N_NODES; n += gridDim.x) {
        const float* row = in + (size_t)n * K;   // wave-uniform -> scalar loads
        float acc = b;
        #pragma unroll
        for (int k = 0; k < K; k++) acc = fmaf(row[k], wcol[k], acc);
        out[((size_t)n*64 + c)*8 + inst] = (f16)acc;
    }
}

// ---------------- K2: CSR build (scan + fill) ----------------
__global__ void __launch_bounds__(SCAN_B)
k_scan1(const int* __restrict__ deg, int* __restrict__ tmp, int* __restrict__ partials) {
    __shared__ int s[SCAN_B];
    int t = threadIdx.x;
    int i = blockIdx.x * SCAN_B + t;
    int v = (i < N_NODES) ? deg[i] : 0;
    s[t] = v;
    __syncthreads();
    #pragma unroll
    for (int off = 1; off < SCAN_B; off <<= 1) {
        int add = (t >= off) ? s[t - off] : 0;
        __syncthreads();
        s[t] += add;
        __syncthreads();
    }
    if (i < N_NODES) tmp[i] = s[t];
    if (t == SCAN_B - 1) partials[blockIdx.x] = s[SCAN_B - 1];
}

__global__ void __launch_bounds__(64)
k_scan2(int* __restrict__ partials) {
    int lane = threadIdx.x;
    int carry = 0;
    for (int base = 0; base < SCAN_NBLK; base += 64) {
        int i = base + lane;
        int v = (i < SCAN_NBLK) ? partials[i] : 0;
        #pragma unroll
        for (int off = 1; off < 64; off <<= 1) {
            int u = __shfl_up(v, off);
            if (lane >= off) v += u;
        }
        if (i < SCAN_NBLK) partials[i] = v + carry;
        carry += __shfl(v, 63);
    }
}

__global__ void __launch_bounds__(SCAN_B)
k_scan3(const int* __restrict__ tmp, const int* __restrict__ partials,
        int* __restrict__ row_ptr, int* __restrict__ cursor) {
    int i = blockIdx.x * SCAN_B + threadIdx.x;
    if (i < N_NODES) {
        int b = blockIdx.x;
        int off = (b > 0) ? partials[b - 1] : 0;
        row_ptr[i + 1] = off + tmp[i];
        cursor[i] = 0;
        if (i == 0) row_ptr[0] = 0;
    }
}

// fill sorted with PRE-MULTIPLIED BYTE OFFSETS (eid*32 = e16 row, src*1024 =
// XLt row) so the main kernel's post-readlane address math is a bare s_add.
__global__ void k_fill(const int* __restrict__ src, const int* __restrict__ dst,
                       const int* __restrict__ row_ptr,
                       int* __restrict__ cursor, int2* __restrict__ sorted_es) {
    int e = blockIdx.x * blockDim.x + threadIdx.x;
    if (e < N_EDGES) {
        int d = dst[e];
        int s = src[e];
        int pos = atomicAdd(&cursor[d], 1);
        sorted_es[row_ptr[d] + pos] = make_int2(e << 5, s << 10);
    }
}

// ---------------- K3: fused GATv2 x8 + LSTM + LayerNorm ----------------
// INSTANCE-SPLIT (round 4): one node per 256-thread block; wave w owns GAT
// instance pair (2w, 2w+1). Rationale: the kernel runs at ~26% of its VALU
// issue-bound -> latency-bound. Splitting the 8 instances across 4 waves
// gives 4x the wave parallelism per node, ~4x shorter per-edge dependent
// regions, and a 16-register weight set per wave. Cross-wave gate combine
// via a 2 KB LDS exchange; wave 0 runs the LSTM+LN tail (FP order identical
// to the single-wave version).
__global__ void __launch_bounds__(256)
k_gat_main(const f16* __restrict__ e16,
           const f16* __restrict__ XLt, const f16* __restrict__ XRt,
           const int* __restrict__ row_ptr, const int2* __restrict__ sorted_es,
           const float* __restrict__ Wex, const float* __restrict__ Weh,
           const float* __restrict__ attx, const float* __restrict__ atth,
           const float* __restrict__ biasx, const float* __restrict__ biash,
           const float* __restrict__ c_prev,
           const float* __restrict__ ln_g, const float* __restrict__ ln_b,
           float* __restrict__ out) {
    int wv = threadIdx.x >> 6;            // instance pair pr = wv
    int lane = threadIdx.x & 63;
    int n = blockIdx.x;                   // one node per block
    int c = lane;
    int hh = c >> 5;
    int ch = c & 31;
    int pr = wv;
    int i0 = 2 * pr, i1 = 2 * pr + 1;

    // Stage packed We columns in LDS: wlds[(inst*8+k2)*64+c] = pk(W[2k2][c],W[2k2+1][c])
    __shared__ u32 wlds[8 * 8 * 64];      // 16 KB
    __shared__ float glds[8][64];         // 2 KB gate exchange
    {
        int tid = threadIdx.x;
        #pragma unroll
        for (int it = 0; it < 16; it++) {
            int idx = it * 256 + tid;     // [0, 4096)
            int inst = idx >> 9;
            int k2 = (idx >> 6) & 7;
            int cc = idx & 63;
            const float* Wsrc = (inst < 4)
                ? (Wex + ((inst * 16 + 2 * k2) * 64 + cc))
                : (Weh + (((inst - 4) * 16 + 2 * k2) * 64 + cc));
            wlds[idx] = h2u(__builtin_amdgcn_cvt_pkrtz(Wsrc[0], Wsrc[64]));
        }
    }
    __syncthreads();

    // att for this wave's instance pair
    h2 attp;
    {
        float a0 = (i0 < 4) ? attx[(i0*2 + hh)*32 + ch] : atth[((i0-4)*2 + hh)*32 + ch];
        float a1 = (i1 < 4) ? attx[(i1*2 + hh)*32 + ch] : atth[((i1-4)*2 + hh)*32 + ch];
        attp = __builtin_amdgcn_cvt_pkrtz(a0, a1);
    }
    // We columns for this wave's 2 instances (16 VGPRs)
    h2 wef[2][8];
    #pragma unroll
    for (int ii = 0; ii < 2; ii++) {
        #pragma unroll
        for (int k2 = 0; k2 < 8; k2++)
            wef[ii][k2] = u2h(wlds[((i0 + ii) * 8 + k2) * 64 + c]);
    }
    // xr dword for this node/channel/instance-pair
    h2 xrp;
    {
        u32 rx = *(const u32*)((const char*)XRt + (((size_t)n*64 + c)*8 + 2*pr)*2);
        xrp = u2h(rx);
    }
    h2 accp = (h2)0, denp = (h2)0;

    const char* e16b = (const char*)e16;
    const char* XLb  = (const char*)XLt;
    int coff = (c << 4) + (pr << 2);      // byte offset of (channel c, pair pr) in XLt row

    int start = row_ptr[n];
    int end = row_ptr[n + 1];
    for (int base = start; base < end; base += 64) {
        int rem = end - base;
        int cnt = rem < 64 ? rem : 64;
        int2 ev = make_int2(0, 0);
        if (base + lane < end) ev = sorted_es[base + lane];
        int eoff_v = ev.x, soff_v = ev.y;   // pre-multiplied byte offsets

        // 2-slot software pipeline: loads for edge j issued at j-2's compute
        uint4 qa0, qa1, qb0, qb1;
        u32 xa, xb;
        auto issueA = [&](int j) {
            int eo = __builtin_amdgcn_readlane(eoff_v, j);
            int so = __builtin_amdgcn_readlane(soff_v, j);
            const uint4* ep = (const uint4*)(e16b + eo);
            qa0 = ep[0]; qa1 = ep[1];
            xa = *(const u32*)(XLb + so + coff);
        };
        auto issueB = [&](int j) {
            int eo = __builtin_amdgcn_readlane(eoff_v, j);
            int so = __builtin_amdgcn_readlane(soff_v, j);
            const uint4* ep = (const uint4*)(e16b + eo);
            qb0 = ep[0]; qb1 = ep[1];
            xb = *(const u32*)(XLb + so + coff);
        };
        auto compute = [&](uint4 q0, uint4 q1, u32 xl_u) {
            h2 es[8] = {u2h(q0.x), u2h(q0.y), u2h(q0.z), u2h(q0.w),
                        u2h(q1.x), u2h(q1.y), u2h(q1.z), u2h(q1.w)};
            h2 xlp = u2h(xl_u);
            h2 s = xlp + xrp;              // v_pk_add_f16
            float m0 = (float)s[0];
            float m1 = (float)s[1];
            #pragma unroll
            for (int k2 = 0; k2 < 8; k2++) {
                m0 = __builtin_amdgcn_fdot2(es[k2], wef[0][k2], m0, false);
                m1 = __builtin_amdgcn_fdot2(es[k2], wef[1][k2], m1, false);
            }
            h2 mm = __builtin_amdgcn_cvt_pkrtz(m0, m1);
            h2 mx = __builtin_elementwise_max(mm, (h2)0);
            h2 mn = __builtin_elementwise_min(mm, (h2)0);
            h2 mr = mn * (h2)0.2f16 + mx;  // leaky_relu, packed
            h2 tp = mr * attp;
            // rotation-reduce within 16-row (DPP, VALU pipe), then xor16 (1 DS op)
            tp = tp + dppmov<0xB1>(tp);
            tp = tp + dppmov<0x4E>(tp);
            tp = tp + dppmov<0x124>(tp);
            tp = tp + dppmov<0x128>(tp);
            tp = tp + swz16(tp);
            // scores tiny: exp without max-subtraction is equivalent
            float p0 = __expf((float)tp[0]);
            float p1 = __expf((float)tp[1]);
            h2 pp = __builtin_amdgcn_cvt_pkrtz(p0, p1);
            denp = denp + pp;
            accp = __builtin_elementwise_fma(pp, xlp, accp);
        };

        if (cnt > 0) issueA(0);
        if (cnt > 1) issueB(1);
        int j = 0;
        while (j < cnt) {
            uint4 q0 = qa0, q1 = qa1;
            u32 xl = xa;
            if (j + 2 < cnt) issueA(j + 2);
            compute(q0, q1, xl);
            j++;
            if (j >= cnt) break;
            q0 = qb0; q1 = qb1; xl = xb;
            if (j + 2 < cnt) issueB(j + 2);
            compute(q0, q1, xl);
            j++;
        }
    }

    // per-wave gate contribution -> LDS
    {
        float b0 = (i0 < 4) ? biasx[i0*64 + c] : biash[(i0-4)*64 + c];
        float b1 = (i1 < 4) ? biasx[i1*64 + c] : biash[(i1-4)*64 + c];
        float v0 = (float)accp[0] / ((float)denp[0] + 1e-16f) + b0;
        float v1 = (float)accp[1] / ((float)denp[1] + 1e-16f) + b1;
        glds[i0][c] = v0;
        glds[i1][c] = v1;
    }
    __syncthreads();
    if (wv != 0) return;

    float gates[4];
    #pragma unroll
    for (int g = 0; g < 4; g++) gates[g] = glds[g][c] + glds[4 + g][c];
    float it = 1.f / (1.f + __expf(-gates[0]));
    float ft = 1.f / (1.f + __expf(-gates[1]));
    float ot = 1.f / (1.f + __expf(-gates[2]));
    float gt = tanhf(gates[3]);
    float cp = c_prev[(size_t)n*64 + c];
    float ct = ft * cp + it * gt;
    float ht = ot * tanhf(ct);
    float s1 = ht;
    #pragma unroll
    for (int off = 32; off >= 1; off >>= 1) s1 += __shfl_xor(s1, off);
    float mu = s1 * (1.f / 64.f);
    float d = ht - mu;
    float s2 = d * d;
    #pragma unroll
    for (int off = 32; off >= 1; off >>= 1) s2 += __shfl_xor(s2, off);
    float var = s2 * (1.f / 64.f);
    float y = d * rsqrtf(var + 1e-5f) * ln_g[c] + ln_b[c];
    out[(size_t)n*64 + c] = y;
    out[(size_t)(N_NODES + n)*64 + c] = ct;
}

extern "C" void kernel_launch(void* const* d_in, const int* in_sizes, int n_in,
                              void* d_out, int out_size, void* d_ws, size_t ws_size,
                              hipStream_t stream) {
    const float* x_t    = (const float*)d_in[0];
    const float* h_prev = (const float*)d_in[1];
    const float* c_prev = (const float*)d_in[2];
    const int*   ei     = (const int*)d_in[3];
    const float* eattr  = (const float*)d_in[4];
    const float* Wm1    = (const float*)d_in[5];
    const float* bm1    = (const float*)d_in[6];
    const float* Wm2    = (const float*)d_in[7];
    const float* bm2    = (const float*)d_in[8];
    const float* Wlx    = (const float*)d_in[9];
    const float* blx    = (const float*)d_in[10];
    const float* Wrx    = (const float*)d_in[11];
    const float* brx    = (const float*)d_in[12];
    const float* Wex    = (const float*)d_in[13];
    const float* attx   = (const float*)d_in[14];
    const float* biasx  = (const float*)d_in[15];
    const float* Wlh    = (const float*)d_in[16];
    const float* blh    = (const float*)d_in[17];
    const float* Wrh    = (const float*)d_in[18];
    const float* brh    = (const float*)d_in[19];
    const float* Weh    = (const float*)d_in[20];
    const float* atth   = (const float*)d_in[21];
    const float* biash  = (const float*)d_in[22];
    const float* ln_g   = (const float*)d_in[23];
    const float* ln_b   = (const float*)d_in[24];

    char* ws = (char*)d_ws;
    f16*   e16     = (f16*)(ws + 0);              // 25,600,000 B
    f16*   XLt     = (f16*)(ws + 25600000);       // 51,200,000 B  [n][64][8]
    f16*   XRt     = (f16*)(ws + 76800000);       // 51,200,000 B  [n][64][8]
    int*   row_ptr = (int*)(ws + 128000000);      //    200,704 B
    int*   degcur  = (int*)(ws + 128200704);      //    200,704 B
    int2*  sorted  = (int2*)(ws + 128401408);     //  6,400,000 B
    int*   scan_tmp = (int*)(ws + 128401408);     // overlaps sorted (dead before k_fill)
    int*   partials = (int*)(ws + 128401408 + 204800);

    const int* srcp = ei;
    const int* dstp = ei + N_EDGES;

    (void)hipMemsetAsync(degcur, 0, N_NODES * sizeof(int), stream);

    k_edge_mlp<<<(N_EDGES + 255) / 256, 256, 0, stream>>>(eattr, Wm1, bm1, Wm2, bm2,
                                                          dstp, degcur, e16);
    k_node_feats<32><<<6250, 512, 0, stream>>>(x_t, Wlx, blx, Wrx, brx, XLt, XRt, 0);
    k_node_feats<64><<<6250, 512, 0, stream>>>(h_prev, Wlh, blh, Wrh, brh, XLt, XRt, 4);
    k_scan1<<<SCAN_NBLK, SCAN_B, 0, stream>>>(degcur, scan_tmp, partials);
    k_scan2<<<1, 64, 0, stream>>>(partials);
    k_scan3<<<SCAN_NBLK, SCAN_B, 0, stream>>>(scan_tmp, partials, row_ptr, degcur);
    k_fill<<<(N_EDGES + 255) / 256, 256, 0, stream>>>(srcp, dstp, row_ptr, degcur, sorted);
    k_gat_main<<<N_NODES, 256, 0, stream>>>(e16, XLt, XRt, row_ptr, sorted,
                                            Wex, Weh, attx, atth, biasx, biash,
                                            c_prev, ln_g, ln_b, (float*)d_out);
}

// Round 5
// 759.282 us; speedup vs baseline: 1.0273x; 1.0273x over previous
//
#include <hip/hip_runtime.h>
#include <math.h>

#define N_NODES 50000
#define N_EDGES 800000
#define SCAN_B 512
#define SCAN_NBLK ((N_NODES + SCAN_B - 1) / SCAN_B)   // 98

typedef unsigned short u16;
typedef unsigned int u32;
typedef _Float16 f16;
typedef __fp16 h2 __attribute__((ext_vector_type(2)));   // matches cvt_pkrtz / fdot2

union U32H2 { u32 u; h2 h; };
__device__ __forceinline__ h2 u2h(u32 x) { U32H2 t; t.u = x; return t.h; }
__device__ __forceinline__ u32 h2u(h2 x) { U32H2 t; t.h = x; return t.u; }

// DPP cross-lane move (VALU pipe). CTRL: 0xB1=xor1(quad), 0x4E=xor2(quad),
// 0x124=row_ror:4, 0x128=row_ror:8. Rotation-reduce: every lane of a 16-row
// ends with the row sum after steps 1,2,ror4,ror8.
template<int CTRL>
__device__ __forceinline__ h2 dppmov(h2 x) {
    return u2h((u32)__builtin_amdgcn_update_dpp(0, (int)h2u(x), CTRL, 0xF, 0xF, true));
}
__device__ __forceinline__ h2 swz16(h2 x) {   // lane ^= 16 within each 32-group
    return u2h((u32)__builtin_amdgcn_ds_swizzle((int)h2u(x), 0x401F));
}

// ---------------- K0: edge MLP (f16 out) + fused degree count ----------------
__global__ void k_edge_mlp(const float* __restrict__ edge_attr,
                           const float* __restrict__ Wm1, const float* __restrict__ bm1,
                           const float* __restrict__ Wm2, const float* __restrict__ bm2,
                           const int* __restrict__ dst, int* __restrict__ deg,
                           f16* __restrict__ e16) {
    int e = blockIdx.x * blockDim.x + threadIdx.x;
    if (e >= N_EDGES) return;
    atomicAdd(&deg[dst[e]], 1);
    const float4* ap = (const float4*)(edge_attr + (size_t)e * 16);
    float a[16];
    #pragma unroll
    for (int i = 0; i < 4; i++) {
        float4 r = ap[i];
        a[4*i] = r.x; a[4*i+1] = r.y; a[4*i+2] = r.z; a[4*i+3] = r.w;
    }
    float g1[16];
    #pragma unroll
    for (int j = 0; j < 16; j++) {
        float v = bm1[j];
        #pragma unroll
        for (int k = 0; k < 16; k++) v = fmaf(a[k], Wm1[k*16 + j], v);
        g1[j] = 0.5f * v * (1.0f + erff(v * 0.70710678118654752f));
    }
    float o[16];
    #pragma unroll
    for (int j = 0; j < 16; j++) {
        float v = bm2[j];
        #pragma unroll
        for (int k = 0; k < 16; k++) v = fmaf(g1[k], Wm2[k*16 + j], v);
        o[j] = v;
    }
    u32 w[8];
    #pragma unroll
    for (int k2 = 0; k2 < 8; k2++) w[k2] = h2u(__builtin_amdgcn_cvt_pkrtz(o[2*k2], o[2*k2+1]));
    uint4* op = (uint4*)(e16 + (size_t)e * 16);
    op[0] = make_uint4(w[0], w[1], w[2], w[3]);
    op[1] = make_uint4(w[4], w[5], w[6], w[7]);
}

// ---------------- K1: node features -> XLt/XRt PAIR-MAJOR f16 ----------------
// Layout: [n][pr(4)][c(64)][i(2)]  (f16 idx = n*512 + pr*128 + c*2 + i).
// Rationale (round 5): the gat kernel's wave pr reads (c, 2pr..2pr+1) for all
// 64 lanes. With the old [n][c][inst] layout that was a stride-16B gather
// touching 16 cache lines per wave (x4 waves = 64 line-requests/edge). Pair-
// major makes each wave's slice 256 B CONTIGUOUS: 4 lines, each fully used,
// 16 line-touches per edge total -- 4x less TA/L1 work.
// 512 threads = 8 waves: wave w<4 -> XL side gate w; w>=4 -> XR side gate w-4.
template<int K>
__global__ void __launch_bounds__(512)
k_node_feats(const float* __restrict__ in,
             const float* __restrict__ Wl, const float* __restrict__ bl,
             const float* __restrict__ Wr, const float* __restrict__ br,
             f16* __restrict__ XLt, f16* __restrict__ XRt, int inst_base) {
    int w = threadIdx.x >> 6;
    int c = threadIdx.x & 63;
    int g = w & 3;
    bool isR = w >= 4;
    const float* W = isR ? Wr : Wl;
    const float* bias = isR ? br : bl;
    f16* out = isR ? XRt : XLt;
    int inst = inst_base + g;
    size_t ooff = (size_t)(inst >> 1) * 128 + (size_t)c * 2 + (inst & 1);
    float wcol[K];
    #pragma unroll
    for (int k = 0; k < K; k++) wcol[k] = W[(g*K + k)*64 + c];
    float b = bias[g*64 + c];
    for (int n = blockIdx.x; n < N_NODES; n += gridDim.x) {
        const float* row = in + (size_t)n * K;   // wave-uniform -> scalar loads
        float acc = b;
        #pragma unroll
        for (int k = 0; k < K; k++) acc = fmaf(row[k], wcol[k], acc);
        out[(size_t)n * 512 + ooff] = (f16)acc;
    }
}

// ---------------- K2: CSR build (scan + fill) ----------------
__global__ void __launch_bounds__(SCAN_B)
k_scan1(const int* __restrict__ deg, int* __restrict__ tmp, int* __restrict__ partials) {
    __shared__ int s[SCAN_B];
    int t = threadIdx.x;
    int i = blockIdx.x * SCAN_B + t;
    int v = (i < N_NODES) ? deg[i] : 0;
    s[t] = v;
    __syncthreads();
    #pragma unroll
    for (int off = 1; off < SCAN_B; off <<= 1) {
        int add = (t >= off) ? s[t - off] : 0;
        __syncthreads();
        s[t] += add;
        __syncthreads();
    }
    if (i < N_NODES) tmp[i] = s[t];
    if (t == SCAN_B - 1) partials[blockIdx.x] = s[SCAN_B - 1];
}

__global__ void __launch_bounds__(64)
k_scan2(int* __restrict__ partials) {
    int lane = threadIdx.x;
    int carry = 0;
    for (int base = 0; base < SCAN_NBLK; base += 64) {
        int i = base + lane;
        int v = (i < SCAN_NBLK) ? partials[i] : 0;
        #pragma unroll
        for (int off = 1; off < 64; off <<= 1) {
            int u = __shfl_up(v, off);
            if (lane >= off) v += u;
        }
        if (i < SCAN_NBLK) partials[i] = v + carry;
        carry += __shfl(v, 63);
    }
}

__global__ void __launch_bounds__(SCAN_B)
k_scan3(const int* __restrict__ tmp, const int* __restrict__ partials,
        int* __restrict__ row_ptr, int* __restrict__ cursor) {
    int i = blockIdx.x * SCAN_B + threadIdx.x;
    if (i < N_NODES) {
        int b = blockIdx.x;
        int off = (b > 0) ? partials[b - 1] : 0;
        row_ptr[i + 1] = off + tmp[i];
        cursor[i] = 0;
        if (i == 0) row_ptr[0] = 0;
    }
}

// fill sorted with PRE-MULTIPLIED BYTE OFFSETS (eid*32 = e16 row, src*1024 =
// XLt row) so the main kernel's post-readlane address math is a bare s_add.
__global__ void k_fill(const int* __restrict__ src, const int* __restrict__ dst,
                       const int* __restrict__ row_ptr,
                       int* __restrict__ cursor, int2* __restrict__ sorted_es) {
    int e = blockIdx.x * blockDim.x + threadIdx.x;
    if (e < N_EDGES) {
        int d = dst[e];
        int s = src[e];
        int pos = atomicAdd(&cursor[d], 1);
        sorted_es[row_ptr[d] + pos] = make_int2(e << 5, s << 10);
    }
}

// ---------------- K3: fused GATv2 x8 + LSTM + LayerNorm ----------------
// INSTANCE-SPLIT + PAIR-MAJOR XL/XR (round 5): one node per 256-thread block;
// wave w owns GAT instance pair (2w, 2w+1). The per-edge XLt read is now a
// fully-coalesced 256-B wave load (4 cache lines, all bytes used) instead of
// a stride-16B gather touching 16 lines. Cross-wave gate combine via 2 KB
// LDS; wave 0 runs the LSTM+LN tail (FP order identical).
__global__ void __launch_bounds__(256)
k_gat_main(const f16* __restrict__ e16,
           const f16* __restrict__ XLt, const f16* __restrict__ XRt,
           const int* __restrict__ row_ptr, const int2* __restrict__ sorted_es,
           const float* __restrict__ Wex, const float* __restrict__ Weh,
           const float* __restrict__ attx, const float* __restrict__ atth,
           const float* __restrict__ biasx, const float* __restrict__ biash,
           const float* __restrict__ c_prev,
           const float* __restrict__ ln_g, const float* __restrict__ ln_b,
           float* __restrict__ out) {
    int wv = threadIdx.x >> 6;            // instance pair pr = wv
    int lane = threadIdx.x & 63;
    int n = blockIdx.x;                   // one node per block
    int c = lane;
    int hh = c >> 5;
    int ch = c & 31;
    int pr = wv;
    int i0 = 2 * pr, i1 = 2 * pr + 1;

    // Stage packed We columns in LDS: wlds[(inst*8+k2)*64+c] = pk(W[2k2][c],W[2k2+1][c])
    __shared__ u32 wlds[8 * 8 * 64];      // 16 KB
    __shared__ float glds[8][64];         // 2 KB gate exchange
    {
        int tid = threadIdx.x;
        #pragma unroll
        for (int it = 0; it < 16; it++) {
            int idx = it * 256 + tid;     // [0, 4096)
            int inst = idx >> 9;
            int k2 = (idx >> 6) & 7;
            int cc = idx & 63;
            const float* Wsrc = (inst < 4)
                ? (Wex + ((inst * 16 + 2 * k2) * 64 + cc))
                : (Weh + (((inst - 4) * 16 + 2 * k2) * 64 + cc));
            wlds[idx] = h2u(__builtin_amdgcn_cvt_pkrtz(Wsrc[0], Wsrc[64]));
        }
    }
    __syncthreads();

    // att for this wave's instance pair
    h2 attp;
    {
        float a0 = (i0 < 4) ? attx[(i0*2 + hh)*32 + ch] : atth[((i0-4)*2 + hh)*32 + ch];
        float a1 = (i1 < 4) ? attx[(i1*2 + hh)*32 + ch] : atth[((i1-4)*2 + hh)*32 + ch];
        attp = __builtin_amdgcn_cvt_pkrtz(a0, a1);
    }
    // We columns for this wave's 2 instances (16 VGPRs)
    h2 wef[2][8];
    #pragma unroll
    for (int ii = 0; ii < 2; ii++) {
        #pragma unroll
        for (int k2 = 0; k2 < 8; k2++)
            wef[ii][k2] = u2h(wlds[((i0 + ii) * 8 + k2) * 64 + c]);
    }
    // xr dword for this node/channel/instance-pair (pair-major: coalesced)
    h2 xrp;
    {
        u32 rx = *(const u32*)((const char*)XRt + (size_t)n*1024 + (pr << 8) + (c << 2));
        xrp = u2h(rx);
    }
    h2 accp = (h2)0, denp = (h2)0;

    const char* e16b = (const char*)e16;
    const char* XLb  = (const char*)XLt;
    int coff = (pr << 8) + (c << 2);      // byte offset of (pair pr, channel c) in XLt row

    int start = row_ptr[n];
    int end = row_ptr[n + 1];
    for (int base = start; base < end; base += 64) {
        int rem = end - base;
        int cnt = rem < 64 ? rem : 64;
        int2 ev = make_int2(0, 0);
        if (base + lane < end) ev = sorted_es[base + lane];
        int eoff_v = ev.x, soff_v = ev.y;   // pre-multiplied byte offsets

        // 2-slot software pipeline: loads for edge j issued at j-2's compute
        uint4 qa0, qa1, qb0, qb1;
        u32 xa, xb;
        auto issueA = [&](int j) {
            int eo = __builtin_amdgcn_readlane(eoff_v, j);
            int so = __builtin_amdgcn_readlane(soff_v, j);
            const uint4* ep = (const uint4*)(e16b + eo);
            qa0 = ep[0]; qa1 = ep[1];
            xa = *(const u32*)(XLb + so + coff);
        };
        auto issueB = [&](int j) {
            int eo = __builtin_amdgcn_readlane(eoff_v, j);
            int so = __builtin_amdgcn_readlane(soff_v, j);
            const uint4* ep = (const uint4*)(e16b + eo);
            qb0 = ep[0]; qb1 = ep[1];
            xb = *(const u32*)(XLb + so + coff);
        };
        auto compute = [&](uint4 q0, uint4 q1, u32 xl_u) {
            h2 es[8] = {u2h(q0.x), u2h(q0.y), u2h(q0.z), u2h(q0.w),
                        u2h(q1.x), u2h(q1.y), u2h(q1.z), u2h(q1.w)};
            h2 xlp = u2h(xl_u);
            h2 s = xlp + xrp;              // v_pk_add_f16
            float m0 = (float)s[0];
            float m1 = (float)s[1];
            #pragma unroll
            for (int k2 = 0; k2 < 8; k2++) {
                m0 = __builtin_amdgcn_fdot2(es[k2], wef[0][k2], m0, false);
                m1 = __builtin_amdgcn_fdot2(es[k2], wef[1][k2], m1, false);
            }
            h2 mm = __builtin_amdgcn_cvt_pkrtz(m0, m1);
            h2 mx = __builtin_elementwise_max(mm, (h2)0);
            h2 mn = __builtin_elementwise_min(mm, (h2)0);
            h2 mr = mn * (h2)0.2f16 + mx;  // leaky_relu, packed
            h2 tp = mr * attp;
            // rotation-reduce within 16-row (DPP, VALU pipe), then xor16 (1 DS op)
            tp = tp + dppmov<0xB1>(tp);
            tp = tp + dppmov<0x4E>(tp);
            tp = tp + dppmov<0x124>(tp);
            tp = tp + dppmov<0x128>(tp);
            tp = tp + swz16(tp);
            // scores tiny: exp without max-subtraction is equivalent
            float p0 = __expf((float)tp[0]);
            float p1 = __expf((float)tp[1]);
            h2 pp = __builtin_amdgcn_cvt_pkrtz(p0, p1);
            denp = denp + pp;
            accp = __builtin_elementwise_fma(pp, xlp, accp);
        };

        if (cnt > 0) issueA(0);
        if (cnt > 1) issueB(1);
        int j = 0;
        while (j < cnt) {
            uint4 q0 = qa0, q1 = qa1;
            u32 xl = xa;
            if (j + 2 < cnt) issueA(j + 2);
            compute(q0, q1, xl);
            j++;
            if (j >= cnt) break;
            q0 = qb0; q1 = qb1; xl = xb;
            if (j + 2 < cnt) issueB(j + 2);
            compute(q0, q1, xl);
            j++;
        }
    }

    // per-wave gate contribution -> LDS
    {
        float b0 = (i0 < 4) ? biasx[i0*64 + c] : biash[(i0-4)*64 + c];
        float b1 = (i1 < 4) ? biasx[i1*64 + c] : biash[(i1-4)*64 + c];
        float v0 = (float)accp[0] / ((float)denp[0] + 1e-16f) + b0;
        float v1 = (float)accp[1] / ((float)denp[1] + 1e-16f) + b1;
        glds[i0][c] = v0;
        glds[i1][c] = v1;
    }
    __syncthreads();
    if (wv != 0) return;

    float gates[4];
    #pragma unroll
    for (int g = 0; g < 4; g++) gates[g] = glds[g][c] + glds[4 + g][c];
    float it = 1.f / (1.f + __expf(-gates[0]));
    float ft = 1.f / (1.f + __expf(-gates[1]));
    float ot = 1.f / (1.f + __expf(-gates[2]));
    float gt = tanhf(gates[3]);
    float cp = c_prev[(size_t)n*64 + c];
    float ct = ft * cp + it * gt;
    float ht = ot * tanhf(ct);
    float s1 = ht;
    #pragma unroll
    for (int off = 32; off >= 1; off >>= 1) s1 += __shfl_xor(s1, off);
    float mu = s1 * (1.f / 64.f);
    float d = ht - mu;
    float s2 = d * d;
    #pragma unroll
    for (int off = 32; off >= 1; off >>= 1) s2 += __shfl_xor(s2, off);
    float var = s2 * (1.f / 64.f);
    float y = d * rsqrtf(var + 1e-5f) * ln_g[c] + ln_b[c];
    out[(size_t)n*64 + c] = y;
    out[(size_t)(N_NODES + n)*64 + c] = ct;
}

extern "C" void kernel_launch(void* const* d_in, const int* in_sizes, int n_in,
                              void* d_out, int out_size, void* d_ws, size_t ws_size,
                              hipStream_t stream) {
    const float* x_t    = (const float*)d_in[0];
    const float* h_prev = (const float*)d_in[1];
    const float* c_prev = (const float*)d_in[2];
    const int*   ei     = (const int*)d_in[3];
    const float* eattr  = (const float*)d_in[4];
    const float* Wm1    = (const float*)d_in[5];
    const float* bm1    = (const float*)d_in[6];
    const float* Wm2    = (const float*)d_in[7];
    const float* bm2    = (const float*)d_in[8];
    const float* Wlx    = (const float*)d_in[9];
    const float* blx    = (const float*)d_in[10];
    const float* Wrx    = (const float*)d_in[11];
    const float* brx    = (const float*)d_in[12];
    const float* Wex    = (const float*)d_in[13];
    const float* attx   = (const float*)d_in[14];
    const float* biasx  = (const float*)d_in[15];
    const float* Wlh    = (const float*)d_in[16];
    const float* blh    = (const float*)d_in[17];
    const float* Wrh    = (const float*)d_in[18];
    const float* brh    = (const float*)d_in[19];
    const float* Weh    = (const float*)d_in[20];
    const float* atth   = (const float*)d_in[21];
    const float* biash  = (const float*)d_in[22];
    const float* ln_g   = (const float*)d_in[23];
    const float* ln_b   = (const float*)d_in[24];

    char* ws = (char*)d_ws;
    f16*   e16     = (f16*)(ws + 0);              // 25,600,000 B
    f16*   XLt     = (f16*)(ws + 25600000);       // 51,200,000 B  [n][pr][c][i]
    f16*   XRt     = (f16*)(ws + 76800000);       // 51,200,000 B  [n][pr][c][i]
    int*   row_ptr = (int*)(ws + 128000000);      //    200,704 B
    int*   degcur  = (int*)(ws + 128200704);      //    200,704 B
    int2*  sorted  = (int2*)(ws + 128401408);     //  6,400,000 B
    int*   scan_tmp = (int*)(ws + 128401408);     // overlaps sorted (dead before k_fill)
    int*   partials = (int*)(ws + 128401408 + 204800);

    const int* srcp = ei;
    const int* dstp = ei + N_EDGES;

    (void)hipMemsetAsync(degcur, 0, N_NODES * sizeof(int), stream);

    k_edge_mlp<<<(N_EDGES + 255) / 256, 256, 0, stream>>>(eattr, Wm1, bm1, Wm2, bm2,
                                                          dstp, degcur, e16);
    k_node_feats<32><<<6250, 512, 0, stream>>>(x_t, Wlx, blx, Wrx, brx, XLt, XRt, 0);
    k_node_feats<64><<<6250, 512, 0, stream>>>(h_prev, Wlh, blh, Wrh, brh, XLt, XRt, 4);
    k_scan1<<<SCAN_NBLK, SCAN_B, 0, stream>>>(degcur, scan_tmp, partials);
    k_scan2<<<1, 64, 0, stream>>>(partials);
    k_scan3<<<SCAN_NBLK, SCAN_B, 0, stream>>>(scan_tmp, partials, row_ptr, degcur);
    k_fill<<<(N_EDGES + 255) / 256, 256, 0, stream>>>(srcp, dstp, row_ptr, degcur, sorted);
    k_gat_main<<<N_NODES, 256, 0, stream>>>(e16, XLt, XRt, row_ptr, sorted,
                                            Wex, Weh, attx, atth, biasx, biash,
                                            c_prev, ln_g, ln_b, (float*)d_out);
}

// Round 6
// 733.069 us; speedup vs baseline: 1.0640x; 1.0358x over previous
//
#include <hip/hip_runtime.h>
#include <math.h>

#define N_NODES 50000
#define N_EDGES 800000
#define SCAN_B 512
#define SCAN_NBLK ((N_NODES + SCAN_B - 1) / SCAN_B)   // 98

typedef unsigned short u16;
typedef unsigned int u32;
typedef _Float16 f16;
typedef __fp16 h2 __attribute__((ext_vector_type(2)));   // matches cvt_pkrtz / fdot2

union U32H2 { u32 u; h2 h; };
__device__ __forceinline__ h2 u2h(u32 x) { U32H2 t; t.u = x; return t.h; }
__device__ __forceinline__ u32 h2u(h2 x) { U32H2 t; t.h = x; return t.u; }

// Force a wave-uniform (SGPR) value into a VGPR. Used to push the e16 row
// loads onto the VECTOR memory path (global_load, vmcnt-counted). Without
// this, the uniform address compiles to s_load (scalar path, lgkmcnt): the
// per-edge ds_swizzle in the reduce then needs s_waitcnt lgkmcnt(0) (scalar
// returns are out-of-order), which drains the e16 prefetches EVERY edge --
// the software pipeline never pipelines, each edge eats a serial K$-miss.
__device__ __forceinline__ u32 s2v(int s) {
    u32 v;
    asm("v_mov_b32 %0, %1" : "=v"(v) : "s"(s));
    return v;
}

// DPP cross-lane move (VALU pipe). CTRL: 0xB1=xor1(quad), 0x4E=xor2(quad),
// 0x124=row_ror:4, 0x128=row_ror:8. Rotation-reduce: every lane of a 16-row
// ends with the row sum after steps 1,2,ror4,ror8.
template<int CTRL>
__device__ __forceinline__ h2 dppmov(h2 x) {
    return u2h((u32)__builtin_amdgcn_update_dpp(0, (int)h2u(x), CTRL, 0xF, 0xF, true));
}
__device__ __forceinline__ h2 swz16(h2 x) {   // lane ^= 16 within each 32-group
    return u2h((u32)__builtin_amdgcn_ds_swizzle((int)h2u(x), 0x401F));
}

// ---------------- K0: edge MLP (f16 out) + fused degree count ----------------
__global__ void k_edge_mlp(const float* __restrict__ edge_attr,
                           const float* __restrict__ Wm1, const float* __restrict__ bm1,
                           const float* __restrict__ Wm2, const float* __restrict__ bm2,
                           const int* __restrict__ dst, int* __restrict__ deg,
                           f16* __restrict__ e16) {
    int e = blockIdx.x * blockDim.x + threadIdx.x;
    if (e >= N_EDGES) return;
    atomicAdd(&deg[dst[e]], 1);
    const float4* ap = (const float4*)(edge_attr + (size_t)e * 16);
    float a[16];
    #pragma unroll
    for (int i = 0; i < 4; i++) {
        float4 r = ap[i];
        a[4*i] = r.x; a[4*i+1] = r.y; a[4*i+2] = r.z; a[4*i+3] = r.w;
    }
    float g1[16];
    #pragma unroll
    for (int j = 0; j < 16; j++) {
        float v = bm1[j];
        #pragma unroll
        for (int k = 0; k < 16; k++) v = fmaf(a[k], Wm1[k*16 + j], v);
        g1[j] = 0.5f * v * (1.0f + erff(v * 0.70710678118654752f));
    }
    float o[16];
    #pragma unroll
    for (int j = 0; j < 16; j++) {
        float v = bm2[j];
        #pragma unroll
        for (int k = 0; k < 16; k++) v = fmaf(g1[k], Wm2[k*16 + j], v);
        o[j] = v;
    }
    u32 w[8];
    #pragma unroll
    for (int k2 = 0; k2 < 8; k2++) w[k2] = h2u(__builtin_amdgcn_cvt_pkrtz(o[2*k2], o[2*k2+1]));
    uint4* op = (uint4*)(e16 + (size_t)e * 16);
    op[0] = make_uint4(w[0], w[1], w[2], w[3]);
    op[1] = make_uint4(w[4], w[5], w[6], w[7]);
}

// ---------------- K1: node features -> XLt/XRt PAIR-MAJOR f16 ----------------
// Layout: [n][pr(4)][c(64)][i(2)]  (f16 idx = n*512 + pr*128 + c*2 + i).
// 512 threads = 8 waves: wave w<4 -> XL side gate w; w>=4 -> XR side gate w-4.
template<int K>
__global__ void __launch_bounds__(512)
k_node_feats(const float* __restrict__ in,
             const float* __restrict__ Wl, const float* __restrict__ bl,
             const float* __restrict__ Wr, const float* __restrict__ br,
             f16* __restrict__ XLt, f16* __restrict__ XRt, int inst_base) {
    int w = threadIdx.x >> 6;
    int c = threadIdx.x & 63;
    int g = w & 3;
    bool isR = w >= 4;
    const float* W = isR ? Wr : Wl;
    const float* bias = isR ? br : bl;
    f16* out = isR ? XRt : XLt;
    int inst = inst_base + g;
    size_t ooff = (size_t)(inst >> 1) * 128 + (size_t)c * 2 + (inst & 1);
    float wcol[K];
    #pragma unroll
    for (int k = 0; k < K; k++) wcol[k] = W[(g*K + k)*64 + c];
    float b = bias[g*64 + c];
    for (int n = blockIdx.x; n < N_NODES; n += gridDim.x) {
        const float* row = in + (size_t)n * K;   // wave-uniform -> scalar loads
        float acc = b;
        #pragma unroll
        for (int k = 0; k < K; k++) acc = fmaf(row[k], wcol[k], acc);
        out[(size_t)n * 512 + ooff] = (f16)acc;
    }
}

// ---------------- K2: CSR build (scan + fill) ----------------
__global__ void __launch_bounds__(SCAN_B)
k_scan1(const int* __restrict__ deg, int* __restrict__ tmp, int* __restrict__ partials) {
    __shared__ int s[SCAN_B];
    int t = threadIdx.x;
    int i = blockIdx.x * SCAN_B + t;
    int v = (i < N_NODES) ? deg[i] : 0;
    s[t] = v;
    __syncthreads();
    #pragma unroll
    for (int off = 1; off < SCAN_B; off <<= 1) {
        int add = (t >= off) ? s[t - off] : 0;
        __syncthreads();
        s[t] += add;
        __syncthreads();
    }
    if (i < N_NODES) tmp[i] = s[t];
    if (t == SCAN_B - 1) partials[blockIdx.x] = s[SCAN_B - 1];
}

__global__ void __launch_bounds__(64)
k_scan2(int* __restrict__ partials) {
    int lane = threadIdx.x;
    int carry = 0;
    for (int base = 0; base < SCAN_NBLK; base += 64) {
        int i = base + lane;
        int v = (i < SCAN_NBLK) ? partials[i] : 0;
        #pragma unroll
        for (int off = 1; off < 64; off <<= 1) {
            int u = __shfl_up(v, off);
            if (lane >= off) v += u;
        }
        if (i < SCAN_NBLK) partials[i] = v + carry;
        carry += __shfl(v, 63);
    }
}

__global__ void __launch_bounds__(SCAN_B)
k_scan3(const int* __restrict__ tmp, const int* __restrict__ partials,
        int* __restrict__ row_ptr, int* __restrict__ cursor) {
    int i = blockIdx.x * SCAN_B + threadIdx.x;
    if (i < N_NODES) {
        int b = blockIdx.x;
        int off = (b > 0) ? partials[b - 1] : 0;
        row_ptr[i + 1] = off + tmp[i];
        cursor[i] = 0;
        if (i == 0) row_ptr[0] = 0;
    }
}

// fill sorted with PRE-MULTIPLIED BYTE OFFSETS (eid*32 = e16 row, src*1024 =
// XLt row) so the main kernel's post-readlane address math is a bare add.
__global__ void k_fill(const int* __restrict__ src, const int* __restrict__ dst,
                       const int* __restrict__ row_ptr,
                       int* __restrict__ cursor, int2* __restrict__ sorted_es) {
    int e = blockIdx.x * blockDim.x + threadIdx.x;
    if (e < N_EDGES) {
        int d = dst[e];
        int s = src[e];
        int pos = atomicAdd(&cursor[d], 1);
        sorted_es[row_ptr[d] + pos] = make_int2(e << 5, s << 10);
    }
}

// ---------------- K3: fused GATv2 x8 + LSTM + LayerNorm ----------------
// INSTANCE-SPLIT + PAIR-MAJOR XL/XR + VECTOR-PATH e16 (round 6): one node per
// 256-thread block; wave w owns GAT instance pair (2w, 2w+1). The e16 row
// loads go through s2v() so they are global_load (vmcnt) rather than s_load
// (lgkmcnt): the per-edge ds_swizzle's forced lgkmcnt(0) no longer drains the
// e16 prefetches, so the 2-deep software pipeline actually overlaps load
// latency with compute.
__global__ void __launch_bounds__(256)
k_gat_main(const f16* __restrict__ e16,
           const f16* __restrict__ XLt, const f16* __restrict__ XRt,
           const int* __restrict__ row_ptr, const int2* __restrict__ sorted_es,
           const float* __restrict__ Wex, const float* __restrict__ Weh,
           const float* __restrict__ attx, const float* __restrict__ atth,
           const float* __restrict__ biasx, const float* __restrict__ biash,
           const float* __restrict__ c_prev,
           const float* __restrict__ ln_g, const float* __restrict__ ln_b,
           float* __restrict__ out) {
    int wv = threadIdx.x >> 6;            // instance pair pr = wv
    int lane = threadIdx.x & 63;
    int n = blockIdx.x;                   // one node per block
    int c = lane;
    int hh = c >> 5;
    int ch = c & 31;
    int pr = wv;
    int i0 = 2 * pr, i1 = 2 * pr + 1;

    // Stage packed We columns in LDS: wlds[(inst*8+k2)*64+c] = pk(W[2k2][c],W[2k2+1][c])
    __shared__ u32 wlds[8 * 8 * 64];      // 16 KB
    __shared__ float glds[8][64];         // 2 KB gate exchange
    {
        int tid = threadIdx.x;
        #pragma unroll
        for (int it = 0; it < 16; it++) {
            int idx = it * 256 + tid;     // [0, 4096)
            int inst = idx >> 9;
            int k2 = (idx >> 6) & 7;
            int cc = idx & 63;
            const float* Wsrc = (inst < 4)
                ? (Wex + ((inst * 16 + 2 * k2) * 64 + cc))
                : (Weh + (((inst - 4) * 16 + 2 * k2) * 64 + cc));
            wlds[idx] = h2u(__builtin_amdgcn_cvt_pkrtz(Wsrc[0], Wsrc[64]));
        }
    }
    __syncthreads();

    // att for this wave's instance pair
    h2 attp;
    {
        float a0 = (i0 < 4) ? attx[(i0*2 + hh)*32 + ch] : atth[((i0-4)*2 + hh)*32 + ch];
        float a1 = (i1 < 4) ? attx[(i1*2 + hh)*32 + ch] : atth[((i1-4)*2 + hh)*32 + ch];
        attp = __builtin_amdgcn_cvt_pkrtz(a0, a1);
    }
    // We columns for this wave's 2 instances (16 VGPRs)
    h2 wef[2][8];
    #pragma unroll
    for (int ii = 0; ii < 2; ii++) {
        #pragma unroll
        for (int k2 = 0; k2 < 8; k2++)
            wef[ii][k2] = u2h(wlds[((i0 + ii) * 8 + k2) * 64 + c]);
    }
    // xr dword for this node/channel/instance-pair (pair-major: coalesced)
    h2 xrp;
    {
        u32 rx = *(const u32*)((const char*)XRt + (size_t)n*1024 + (pr << 8) + (c << 2));
        xrp = u2h(rx);
    }
    h2 accp = (h2)0, denp = (h2)0;

    const char* e16b = (const char*)e16;
    const char* XLb  = (const char*)XLt;
    int coff = (pr << 8) + (c << 2);      // byte offset of (pair pr, channel c) in XLt row

    int start = row_ptr[n];
    int end = row_ptr[n + 1];
    for (int base = start; base < end; base += 64) {
        int rem = end - base;
        int cnt = rem < 64 ? rem : 64;
        int2 ev = make_int2(0, 0);
        if (base + lane < end) ev = sorted_es[base + lane];
        int eoff_v = ev.x, soff_v = ev.y;   // pre-multiplied byte offsets

        // 2-slot software pipeline: loads for edge j issued at j-2's compute.
        // e16 address goes through s2v() -> VGPR -> vector load (vmcnt).
        uint4 qa0, qa1, qb0, qb1;
        u32 xa, xb;
        auto issueA = [&](int j) {
            int eo = __builtin_amdgcn_readlane(eoff_v, j);
            int so = __builtin_amdgcn_readlane(soff_v, j);
            const uint4* ep = (const uint4*)(e16b + s2v(eo));
            qa0 = ep[0]; qa1 = ep[1];
            xa = *(const u32*)(XLb + so + coff);
        };
        auto issueB = [&](int j) {
            int eo = __builtin_amdgcn_readlane(eoff_v, j);
            int so = __builtin_amdgcn_readlane(soff_v, j);
            const uint4* ep = (const uint4*)(e16b + s2v(eo));
            qb0 = ep[0]; qb1 = ep[1];
            xb = *(const u32*)(XLb + so + coff);
        };
        auto compute = [&](uint4 q0, uint4 q1, u32 xl_u) {
            h2 es[8] = {u2h(q0.x), u2h(q0.y), u2h(q0.z), u2h(q0.w),
                        u2h(q1.x), u2h(q1.y), u2h(q1.z), u2h(q1.w)};
            h2 xlp = u2h(xl_u);
            h2 s = xlp + xrp;              // v_pk_add_f16
            float m0 = (float)s[0];
            float m1 = (float)s[1];
            #pragma unroll
            for (int k2 = 0; k2 < 8; k2++) {
                m0 = __builtin_amdgcn_fdot2(es[k2], wef[0][k2], m0, false);
                m1 = __builtin_amdgcn_fdot2(es[k2], wef[1][k2], m1, false);
            }
            h2 mm = __builtin_amdgcn_cvt_pkrtz(m0, m1);
            h2 mx = __builtin_elementwise_max(mm, (h2)0);
            h2 mn = __builtin_elementwise_min(mm, (h2)0);
            h2 mr = mn * (h2)0.2f16 + mx;  // leaky_relu, packed
            h2 tp = mr * attp;
            // rotation-reduce within 16-row (DPP, VALU pipe), then xor16 (1 DS op)
            tp = tp + dppmov<0xB1>(tp);
            tp = tp + dppmov<0x4E>(tp);
            tp = tp + dppmov<0x124>(tp);
            tp = tp + dppmov<0x128>(tp);
            tp = tp + swz16(tp);
            // scores tiny: exp without max-subtraction is equivalent
            float p0 = __expf((float)tp[0]);
            float p1 = __expf((float)tp[1]);
            h2 pp = __builtin_amdgcn_cvt_pkrtz(p0, p1);
            denp = denp + pp;
            accp = __builtin_elementwise_fma(pp, xlp, accp);
        };

        if (cnt > 0) issueA(0);
        if (cnt > 1) issueB(1);
        int j = 0;
        while (j < cnt) {
            uint4 q0 = qa0, q1 = qa1;
            u32 xl = xa;
            if (j + 2 < cnt) issueA(j + 2);
            compute(q0, q1, xl);
            j++;
            if (j >= cnt) break;
            q0 = qb0; q1 = qb1; xl = xb;
            if (j + 2 < cnt) issueB(j + 2);
            compute(q0, q1, xl);
            j++;
        }
    }

    // per-wave gate contribution -> LDS
    {
        float b0 = (i0 < 4) ? biasx[i0*64 + c] : biash[(i0-4)*64 + c];
        float b1 = (i1 < 4) ? biasx[i1*64 + c] : biash[(i1-4)*64 + c];
        float v0 = (float)accp[0] / ((float)denp[0] + 1e-16f) + b0;
        float v1 = (float)accp[1] / ((float)denp[1] + 1e-16f) + b1;
        glds[i0][c] = v0;
        glds[i1][c] = v1;
    }
    __syncthreads();
    if (wv != 0) return;

    float gates[4];
    #pragma unroll
    for (int g = 0; g < 4; g++) gates[g] = glds[g][c] + glds[4 + g][c];
    float it = 1.f / (1.f + __expf(-gates[0]));
    float ft = 1.f / (1.f + __expf(-gates[1]));
    float ot = 1.f / (1.f + __expf(-gates[2]));
    float gt = tanhf(gates[3]);
    float cp = c_prev[(size_t)n*64 + c];
    float ct = ft * cp + it * gt;
    float ht = ot * tanhf(ct);
    float s1 = ht;
    #pragma unroll
    for (int off = 32; off >= 1; off >>= 1) s1 += __shfl_xor(s1, off);
    float mu = s1 * (1.f / 64.f);
    float d = ht - mu;
    float s2 = d * d;
    #pragma unroll
    for (int off = 32; off >= 1; off >>= 1) s2 += __shfl_xor(s2, off);
    float var = s2 * (1.f / 64.f);
    float y = d * rsqrtf(var + 1e-5f) * ln_g[c] + ln_b[c];
    out[(size_t)n*64 + c] = y;
    out[(size_t)(N_NODES + n)*64 + c] = ct;
}

extern "C" void kernel_launch(void* const* d_in, const int* in_sizes, int n_in,
                              void* d_out, int out_size, void* d_ws, size_t ws_size,
                              hipStream_t stream) {
    const float* x_t    = (const float*)d_in[0];
    const float* h_prev = (const float*)d_in[1];
    const float* c_prev = (const float*)d_in[2];
    const int*   ei     = (const int*)d_in[3];
    const float* eattr  = (const float*)d_in[4];
    const float* Wm1    = (const float*)d_in[5];
    const float* bm1    = (const float*)d_in[6];
    const float* Wm2    = (const float*)d_in[7];
    const float* bm2    = (const float*)d_in[8];
    const float* Wlx    = (const float*)d_in[9];
    const float* blx    = (const float*)d_in[10];
    const float* Wrx    = (const float*)d_in[11];
    const float* brx    = (const float*)d_in[12];
    const float* Wex    = (const float*)d_in[13];
    const float* attx   = (const float*)d_in[14];
    const float* biasx  = (const float*)d_in[15];
    const float* Wlh    = (const float*)d_in[16];
    const float* blh    = (const float*)d_in[17];
    const float* Wrh    = (const float*)d_in[18];
    const float* brh    = (const float*)d_in[19];
    const float* Weh    = (const float*)d_in[20];
    const float* atth   = (const float*)d_in[21];
    const float* biash  = (const float*)d_in[22];
    const float* ln_g   = (const float*)d_in[23];
    const float* ln_b   = (const float*)d_in[24];

    char* ws = (char*)d_ws;
    f16*   e16     = (f16*)(ws + 0);              // 25,600,000 B
    f16*   XLt     = (f16*)(ws + 25600000);       // 51,200,000 B  [n][pr][c][i]
    f16*   XRt     = (f16*)(ws + 76800000);       // 51,200,000 B  [n][pr][c][i]
    int*   row_ptr = (int*)(ws + 128000000);      //    200,704 B
    int*   degcur  = (int*)(ws + 128200704);      //    200,704 B
    int2*  sorted  = (int2*)(ws + 128401408);     //  6,400,000 B
    int*   scan_tmp = (int*)(ws + 128401408);     // overlaps sorted (dead before k_fill)
    int*   partials = (int*)(ws + 128401408 + 204800);

    const int* srcp = ei;
    const int* dstp = ei + N_EDGES;

    (void)hipMemsetAsync(degcur, 0, N_NODES * sizeof(int), stream);

    k_edge_mlp<<<(N_EDGES + 255) / 256, 256, 0, stream>>>(eattr, Wm1, bm1, Wm2, bm2,
                                                          dstp, degcur, e16);
    k_node_feats<32><<<6250, 512, 0, stream>>>(x_t, Wlx, blx, Wrx, brx, XLt, XRt, 0);
    k_node_feats<64><<<6250, 512, 0, stream>>>(h_prev, Wlh, blh, Wrh, brh, XLt, XRt, 4);
    k_scan1<<<SCAN_NBLK, SCAN_B, 0, stream>>>(degcur, scan_tmp, partials);
    k_scan2<<<1, 64, 0, stream>>>(partials);
    k_scan3<<<SCAN_NBLK, SCAN_B, 0, stream>>>(scan_tmp, partials, row_ptr, degcur);
    k_fill<<<(N_EDGES + 255) / 256, 256, 0, stream>>>(srcp, dstp, row_ptr, degcur, sorted);
    k_gat_main<<<N_NODES, 256, 0, stream>>>(e16, XLt, XRt, row_ptr, sorted,
                                            Wex, Weh, attx, atth, biasx, biash,
                                            c_prev, ln_g, ln_b, (float*)d_out);
}